// Round 18
// baseline (56.809 us; speedup 1.0000x reference)
//
#include <hip/hip_runtime.h>
#include <math.h>

#define C_IN  128
#define C_HID 256
#define HGT   64
#define WID   128
#define NBATCH 16
#define HW (HGT * WID)

typedef unsigned int   uint32;
typedef unsigned short u16;
typedef float f32x4  __attribute__((ext_vector_type(4)));
typedef short bf16x8 __attribute__((ext_vector_type(8)));

__device__ __forceinline__ uint32 f2bf_bits(float f) {
    uint32 u = __float_as_uint(f);
    u = (u + 0x7fff + ((u >> 16) & 1)) >> 16;   // RNE
    return u;
}
__device__ __forceinline__ float qclip(float v) {
    return fminf(fmaxf(v, -128.0f), 127.0f);
}

// ============ quant: per-tensor symmetric int8 fake-quant + repack ============
// block 0: dw1 -> qdw1T[9][128]
// block 1: pw1 -> Blin (MFMA-frag bf16 ints) + scales[0]
// block 3: pw2+dw2 -> W18lin (combined dw2*pw2 weights, bf16 MFMA-frag) + dotbias
__global__ __launch_bounds__(1024) void quant4_kernel(
    const float* __restrict__ dw1, const float* __restrict__ pw1,
    const float* __restrict__ dw2, const float* __restrict__ pw2,
    const float* __restrict__ db2,
    float* __restrict__ qdw1T, u16* __restrict__ Blin,
    u16* __restrict__ W18lin, float* __restrict__ scales)
{
    const float* w; int n;
    switch (blockIdx.x) {
        case 0:  w = dw1; n = C_IN * 9;    break;
        case 1:  w = pw1; n = C_HID * C_IN; break;
        case 2:  w = dw2; n = C_HID * 9;   break;
        default: w = pw2; n = 2 * C_HID;   break;
    }
    __shared__ float sm[1024];
    int tid = threadIdx.x;
    const f32x4* w4 = (const f32x4*)w;
    int n4 = n >> 2;
    float m = 0.0f;
    #pragma unroll 4
    for (int i = tid; i < n4; i += 1024) {
        f32x4 v = w4[i];
        m = fmaxf(m, fmaxf(fmaxf(fabsf(v.x), fabsf(v.y)),
                           fmaxf(fabsf(v.z), fabsf(v.w))));
    }
    sm[tid] = m;
    __syncthreads();
    for (int s = 512; s > 0; s >>= 1) {
        if (tid < s) sm[tid] = fmaxf(sm[tid], sm[tid + s]);
        __syncthreads();
    }
    const float scale = sm[0] / 127.0f;

    if (blockIdx.x == 0) {
        for (int i = tid; i < C_IN * 9; i += 1024) {
            int t = i >> 7, cin = i & 127;
            float v = qclip(rintf(dw1[cin * 9 + t] / scale));
            qdw1T[i] = v * scale;
        }
    } else if (blockIdx.x == 1) {
        if (tid == 0) scales[0] = scale;
        // slot s = (kstep*16 + cofrag)*64 + lane; each slot = 8 bf16 (16B)
        #pragma unroll
        for (int i = tid; i < 4096; i += 1024) {
            int kstep = i >> 10;
            int cf    = (i >> 6) & 15;
            int l     = i & 63;
            int co    = cf * 16 + (l & 15);
            int k0    = kstep * 32 + ((l >> 4) << 3);
            const float* src = pw1 + (size_t)co * C_IN + k0;
            f32x4 a = *(const f32x4*)src;
            f32x4 b = *(const f32x4*)(src + 4);
            float vv[8] = {a.x, a.y, a.z, a.w, b.x, b.y, b.z, b.w};
            uint32 pk[4];
            #pragma unroll
            for (int p = 0; p < 4; ++p) {
                float v0 = qclip(rintf(vv[2 * p]     / scale));
                float v1 = qclip(rintf(vv[2 * p + 1] / scale));
                pk[p] = f2bf_bits(v0) | (f2bf_bits(v1) << 16);   // ints exact in bf16
            }
            ((uint4*)Blin)[i] = make_uint4(pk[0], pk[1], pk[2], pk[3]);
        }
    } else if (blockIdx.x == 2) {
        // dw2 handled in block 3
    } else {
        const float s_p = scale;   // pw2 scale
        __syncthreads();

        // second reduction: max|dw2| (2304 = 576 f32x4)
        const f32x4* d4 = (const f32x4*)dw2;
        float md = 0.0f;
        for (int i = tid; i < 576; i += 1024) {
            f32x4 v = d4[i];
            md = fmaxf(md, fmaxf(fmaxf(fabsf(v.x), fabsf(v.y)),
                                 fmaxf(fabsf(v.z), fabsf(v.w))));
        }
        sm[tid] = md;
        __syncthreads();
        for (int s = 512; s > 0; s >>= 1) {
            if (tid < s) sm[tid] = fmaxf(sm[tid], sm[tid + s]);
            __syncthreads();
        }
        const float s_d = sm[0] / 127.0f;

        // W18lin: slot = (ks*2 + jt)*64 + lane; j = jt*16 + (lane&15),
        // ch0 = ks*32 + (lane>>4)*8. W18[j][ch] = qdw2(ch, j>>1) * qpw2(j&1, ch).
        {
            int ks  = tid >> 7;
            int jt  = (tid >> 6) & 1;
            int l   = tid & 63;
            int j   = jt * 16 + (l & 15);
            int ch0 = ks * 32 + ((l >> 4) << 3);
            uint32 pk[4] = {0, 0, 0, 0};
            if (j < 18) {
                int t9 = j >> 1, o = j & 1;
                float wv[8];
                #pragma unroll
                for (int p = 0; p < 8; ++p) {
                    int ch = ch0 + p;
                    float qd = qclip(rintf(dw2[ch * 9 + t9] / s_d)) * s_d;
                    float qp = qclip(rintf(pw2[o * C_HID + ch] / s_p)) * s_p;
                    wv[p] = qd * qp;
                }
                #pragma unroll
                for (int p = 0; p < 4; ++p)
                    pk[p] = f2bf_bits(wv[2 * p]) | (f2bf_bits(wv[2 * p + 1]) << 16);
            }
            ((uint4*)W18lin)[tid] = make_uint4(pk[0], pk[1], pk[2], pk[3]);
        }

        // dotbias[o] = sum_ch qpw2[o][ch] * db2[ch]
        #pragma unroll
        for (int o = 0; o < 2; ++o) {
            __syncthreads();
            if (tid < 256) {
                float qv = qclip(rintf(pw2[o * C_HID + tid] / s_p)) * s_p;
                sm[tid] = qv * db2[tid];
            }
            __syncthreads();
            for (int s = 128; s > 0; s >>= 1) {
                if (tid < s) sm[tid] += sm[tid + s];
                __syncthreads();
            }
            if (tid == 0) scales[1 + o] = sm[0];
        }
    }
}

// ============ fused half-row block: dw1 + MFMA pw1 + ReLU + MFMA W18 -> Mg ============
// One block per (nb, y, xh): 64 px half-row. 512 threads, ~38.5 KB LDS -> 4 blocks/CU.
// Emits raw M[18][64] (no x-gather; that moves to gather_out).
__global__ __launch_bounds__(512, 4) void fused_main(
    const float* __restrict__ x,
    const float* __restrict__ qdw1T, const float* __restrict__ db1,
    const u16* __restrict__ Blin, const float* __restrict__ pb1,
    const u16* __restrict__ W18lin,
    const float* __restrict__ scales,
    float* __restrict__ Mg)
{
    __shared__ __align__(16) unsigned char smem_raw[64 * 264 * 2];   // 33792 B
    __shared__ float Ml[18][66];                                      // 4752 B
    u16 (*h1s)[140]  = (u16 (*)[140])smem_raw;   // phase 1-2: 64px x 128k bf16 (17.9 KB)
    u16 (*h2pm)[264] = (u16 (*)[264])smem_raw;   // epilogue+phase 3: [px][ch]

    const int bid = blockIdx.x;
    const int swz = (bid & 7) * 256 + (bid >> 3);   // XCD-bijective (2048 % 8 == 0)
    const int nb  = swz >> 7;
    const int y   = (swz >> 1) & 63;
    const int xh  = swz & 1;
    const int pxb0 = xh << 6;
    const int tid = threadIdx.x;
    const int wave = tid >> 6, lane = tid & 63;

    // ---------- phase 1: depthwise 1 -> h1s (4 cin x 4 px per thread) ----------
    {
        const int q = tid & 15, g = tid >> 4;     // q: px group (16), g: cin group (32)
        const int px0 = q << 2, cin0 = g << 2;
        // lane = (g&3)*16 + q: q-neighbors are lane-neighbors (same cin group);
        // q=0/15 masks cover the 16-lane group boundaries.

        f32x4 bia = *(const f32x4*)(db1 + cin0);
        float a32[4][4];
        #pragma unroll
        for (int c = 0; c < 4; ++c)
            #pragma unroll
            for (int p = 0; p < 4; ++p) a32[c][p] = ((const float*)&bia)[c];

        #pragma unroll
        for (int ky = 0; ky < 3; ++ky) {
            int yy = y + ky - 1;
            if (yy < 0 || yy >= HGT) continue;
            const float* rowbase = x + (((size_t)nb * C_IN + cin0) * HGT + yy) * WID + pxb0;

            f32x4 mid[4];
            #pragma unroll
            for (int c = 0; c < 4; ++c)
                mid[c] = *(const f32x4*)(rowbase + (size_t)c * HW + px0);

            float w3[3][4];
            #pragma unroll
            for (int kx = 0; kx < 3; ++kx) {
                f32x4 wv = *(const f32x4*)(qdw1T + (ky * 3 + kx) * C_IN + cin0);
                w3[kx][0] = wv.x; w3[kx][1] = wv.y; w3[kx][2] = wv.z; w3[kx][3] = wv.w;
            }

            #pragma unroll
            for (int c = 0; c < 4; ++c) {
                const float* rowc = rowbase + (size_t)c * HW;
                float lf = __shfl_up(mid[c].w, 1);     // lane-1's px0+3 = our px0-1
                float rt = __shfl_down(mid[c].x, 1);   // lane+1's px0   = our px0+4
                if (q == 0)  lf = xh        ? rowc[px0 - 1] : 0.0f;   // block-edge halo
                if (q == 15) rt = (xh == 0) ? rowc[px0 + 4] : 0.0f;
                float seg[6] = {lf, mid[c].x, mid[c].y, mid[c].z, mid[c].w, rt};
                #pragma unroll
                for (int kx = 0; kx < 3; ++kx)
                    #pragma unroll
                    for (int p = 0; p < 4; ++p)
                        a32[c][p] = fmaf(w3[kx][c], seg[p + kx], a32[c][p]);
            }
        }

        #pragma unroll
        for (int p = 0; p < 4; ++p) {
            uint2 pk;
            pk.x = f2bf_bits(a32[0][p]) | (f2bf_bits(a32[1][p]) << 16);
            pk.y = f2bf_bits(a32[2][p]) | (f2bf_bits(a32[3][p]) << 16);
            *(uint2*)&h1s[px0 + p][cin0] = pk;
        }
    }
    __syncthreads();

    // ---------- phase 2: MFMA pw1 (C = 64px x 256co) ----------
    const int l15 = lane & 15, l4 = lane >> 4;
    const int pxt = wave & 3;           // px 16-tile
    const int coh = wave >> 2;          // co half (128 each)
    const int px0w = pxt << 4;
    const float bscale = scales[0];

    f32x4 acc[8];
    #pragma unroll
    for (int c = 0; c < 8; ++c) acc[c] = f32x4{0, 0, 0, 0};

    const bf16x8* BL = (const bf16x8*)Blin;

    #pragma unroll
    for (int ks = 0; ks < 4; ++ks) {
        bf16x8 afrag = *(const bf16x8*)&h1s[px0w + l15][ks * 32 + l4 * 8];
        #pragma unroll
        for (int c = 0; c < 8; ++c) {
            bf16x8 bfrag = BL[(ks * 16 + coh * 8 + c) * 64 + lane];
            acc[c] = __builtin_amdgcn_mfma_f32_16x16x32_bf16(afrag, bfrag, acc[c], 0, 0, 0);
        }
    }

    __syncthreads();   // all MFMA reads of h1s complete; smem becomes h2pm

    // epilogue: scale+bias+ReLU, pack, write px-major [px][ch]
    #pragma unroll
    for (int c = 0; c < 8; ++c) {
        int co = coh * 128 + c * 16 + l15;
        int pxb = px0w + l4 * 4;
        float bias = pb1[co];
        #pragma unroll
        for (int i = 0; i < 4; ++i) {
            float v = fmaxf(fmaf(acc[c][i], bscale, bias), 0.0f);
            h2pm[pxb + i][co] = (u16)f2bf_bits(v);
        }
    }
    __syncthreads();

    // ---------- phase 3: MFMA M[64px][32j] = h2pm[64][256] x W18^T ----------
    // 8 waves = 4 px-tiles x 2 j-tiles
    {
        const int pxt3 = wave & 3;
        const int jt   = wave >> 2;
        const int px0t = pxt3 << 4;
        const bf16x8* WL = (const bf16x8*)W18lin;

        f32x4 acc2 = f32x4{0, 0, 0, 0};
        #pragma unroll 2
        for (int ks = 0; ks < 8; ++ks) {
            bf16x8 af = *(const bf16x8*)&h2pm[px0t + l15][ks * 32 + l4 * 8];
            bf16x8 bf = WL[(ks * 2 + jt) * 64 + lane];
            acc2 = __builtin_amdgcn_mfma_f32_16x16x32_bf16(af, bf, acc2, 0, 0, 0);
        }

        int j = jt * 16 + l15;
        if (j < 18) {
            #pragma unroll
            for (int i = 0; i < 4; ++i)
                Ml[j][px0t + l4 * 4 + i] = acc2[i];
        }
    }
    __syncthreads();

    // stream Ml -> Mg (coalesced)
    {
        float* base = Mg + (size_t)swz * (18 * 64);
        for (int t = tid; t < 18 * 64; t += 512)
            base[t] = Ml[t >> 6][t & 63];
    }
}

// ==== gather: out[o][y][px] = consts + sum_{ky,kx} M_{y+ky-1,xh'}[j(ky,kx,o)][px'] ====
__global__ __launch_bounds__(512) void gather_out(
    const float* __restrict__ Mg, const float* __restrict__ pb2,
    const float* __restrict__ scales, float* __restrict__ out)
{
    int idx = blockIdx.x * 512 + threadIdx.x;
    int px = idx & 127;
    int yy = (idx >> 7) & 63;
    int o  = (idx >> 13) & 1;
    int nb = idx >> 14;
    float v = pb2[o] + scales[1 + o];
    #pragma unroll
    for (int ky = 0; ky < 3; ++ky) {
        int z = yy + ky - 1;   // cross-correlation: tap ky reads source row y+ky-1
        if (z < 0 || z >= HGT) continue;
        #pragma unroll
        for (int kx = 0; kx < 3; ++kx) {
            int pxs = px + kx - 1;
            if (pxs < 0 || pxs >= WID) continue;
            int xh2 = pxs >> 6, px2 = pxs & 63;
            int j = (ky * 3 + kx) * 2 + o;
            v += Mg[((size_t)(((nb * 64 + z) << 1) + xh2) * 18 + j) * 64 + px2];
        }
    }
    out[idx] = v;
}

extern "C" void kernel_launch(void* const* d_in, const int* in_sizes, int n_in,
                              void* d_out, int out_size, void* d_ws, size_t ws_size,
                              hipStream_t stream) {
    const float* x   = (const float*)d_in[0];
    const float* dw1 = (const float*)d_in[1];
    const float* db1 = (const float*)d_in[2];
    const float* pw1 = (const float*)d_in[3];
    const float* pb1 = (const float*)d_in[4];
    const float* dw2 = (const float*)d_in[5];
    const float* db2 = (const float*)d_in[6];
    const float* pw2 = (const float*)d_in[7];
    const float* pb2 = (const float*)d_in[8];
    float* out = (float*)d_out;

    char* wsb = (char*)d_ws;
    u16*   Blin   = (u16*)wsb;                          // 65536 B
    float* qdw1T  = (float*)(wsb + 65536);              // 4608 B
    float* scales = (float*)(wsb + 65536 + 4608);       // 64 B
    u16*   W18lin = (u16*)(wsb + 65536 + 4608 + 64);    // 16384 B
    float* Mg     = (float*)(wsb + 98304);              // 2048*18*64*4 = 9.44 MB

    quant4_kernel<<<4, 1024, 0, stream>>>(dw1, pw1, dw2, pw2, db2,
                                          qdw1T, Blin, W18lin, scales);

    fused_main<<<NBATCH * HGT * 2, 512, 0, stream>>>(
        x, qdw1T, db1, Blin, pb1, W18lin, scales, Mg);

    gather_out<<<512, 512, 0, stream>>>(Mg, pb2, scales, out);
}

// Round 19
// 55.825 us; speedup vs baseline: 1.0176x; 1.0176x over previous
//
#include <hip/hip_runtime.h>
#include <math.h>

#define C_IN  128
#define C_HID 256
#define HGT   64
#define WID   128
#define NBATCH 16
#define HW (HGT * WID)

typedef unsigned int   uint32;
typedef unsigned short u16;
typedef float f32x4  __attribute__((ext_vector_type(4)));
typedef short bf16x8 __attribute__((ext_vector_type(8)));

__device__ __forceinline__ uint32 f2bf_bits(float f) {
    uint32 u = __float_as_uint(f);
    u = (u + 0x7fff + ((u >> 16) & 1)) >> 16;   // RNE
    return u;
}
__device__ __forceinline__ float qclip(float v) {
    return fminf(fmaxf(v, -128.0f), 127.0f);
}

// ============ quant: per-tensor symmetric int8 fake-quant + repack ============
// block 0: dw1 -> qdw1T[9][128]
// block 1: pw1 -> Blin (MFMA-frag bf16 ints) + scales[0]
// block 3: pw2+dw2 -> W18lin (combined dw2*pw2 weights, bf16 MFMA-frag) + dotbias
__global__ __launch_bounds__(1024) void quant4_kernel(
    const float* __restrict__ dw1, const float* __restrict__ pw1,
    const float* __restrict__ dw2, const float* __restrict__ pw2,
    const float* __restrict__ db2,
    float* __restrict__ qdw1T, u16* __restrict__ Blin,
    u16* __restrict__ W18lin, float* __restrict__ scales)
{
    const float* w; int n;
    switch (blockIdx.x) {
        case 0:  w = dw1; n = C_IN * 9;    break;
        case 1:  w = pw1; n = C_HID * C_IN; break;
        case 2:  w = dw2; n = C_HID * 9;   break;
        default: w = pw2; n = 2 * C_HID;   break;
    }
    __shared__ float sm[1024];
    int tid = threadIdx.x;
    const f32x4* w4 = (const f32x4*)w;
    int n4 = n >> 2;
    float m = 0.0f;
    #pragma unroll 4
    for (int i = tid; i < n4; i += 1024) {
        f32x4 v = w4[i];
        m = fmaxf(m, fmaxf(fmaxf(fabsf(v.x), fabsf(v.y)),
                           fmaxf(fabsf(v.z), fabsf(v.w))));
    }
    sm[tid] = m;
    __syncthreads();
    for (int s = 512; s > 0; s >>= 1) {
        if (tid < s) sm[tid] = fmaxf(sm[tid], sm[tid + s]);
        __syncthreads();
    }
    const float scale = sm[0] / 127.0f;

    if (blockIdx.x == 0) {
        for (int i = tid; i < C_IN * 9; i += 1024) {
            int t = i >> 7, cin = i & 127;
            float v = qclip(rintf(dw1[cin * 9 + t] / scale));
            qdw1T[i] = v * scale;
        }
    } else if (blockIdx.x == 1) {
        if (tid == 0) scales[0] = scale;
        // slot s = (kstep*16 + cofrag)*64 + lane; each slot = 8 bf16 (16B)
        #pragma unroll
        for (int i = tid; i < 4096; i += 1024) {
            int kstep = i >> 10;
            int cf    = (i >> 6) & 15;
            int l     = i & 63;
            int co    = cf * 16 + (l & 15);
            int k0    = kstep * 32 + ((l >> 4) << 3);
            const float* src = pw1 + (size_t)co * C_IN + k0;
            f32x4 a = *(const f32x4*)src;
            f32x4 b = *(const f32x4*)(src + 4);
            float vv[8] = {a.x, a.y, a.z, a.w, b.x, b.y, b.z, b.w};
            uint32 pk[4];
            #pragma unroll
            for (int p = 0; p < 4; ++p) {
                float v0 = qclip(rintf(vv[2 * p]     / scale));
                float v1 = qclip(rintf(vv[2 * p + 1] / scale));
                pk[p] = f2bf_bits(v0) | (f2bf_bits(v1) << 16);   // ints exact in bf16
            }
            ((uint4*)Blin)[i] = make_uint4(pk[0], pk[1], pk[2], pk[3]);
        }
    } else if (blockIdx.x == 2) {
        // dw2 handled in block 3
    } else {
        const float s_p = scale;   // pw2 scale
        __syncthreads();

        // second reduction: max|dw2| (2304 = 576 f32x4)
        const f32x4* d4 = (const f32x4*)dw2;
        float md = 0.0f;
        for (int i = tid; i < 576; i += 1024) {
            f32x4 v = d4[i];
            md = fmaxf(md, fmaxf(fmaxf(fabsf(v.x), fabsf(v.y)),
                                 fmaxf(fabsf(v.z), fabsf(v.w))));
        }
        sm[tid] = md;
        __syncthreads();
        for (int s = 512; s > 0; s >>= 1) {
            if (tid < s) sm[tid] = fmaxf(sm[tid], sm[tid + s]);
            __syncthreads();
        }
        const float s_d = sm[0] / 127.0f;

        // W18lin: slot = (ks*2 + jt)*64 + lane; j = jt*16 + (lane&15),
        // ch0 = ks*32 + (lane>>4)*8. W18[j][ch] = qdw2(ch, j>>1) * qpw2(j&1, ch).
        {
            int ks  = tid >> 7;
            int jt  = (tid >> 6) & 1;
            int l   = tid & 63;
            int j   = jt * 16 + (l & 15);
            int ch0 = ks * 32 + ((l >> 4) << 3);
            uint32 pk[4] = {0, 0, 0, 0};
            if (j < 18) {
                int t9 = j >> 1, o = j & 1;
                float wv[8];
                #pragma unroll
                for (int p = 0; p < 8; ++p) {
                    int ch = ch0 + p;
                    float qd = qclip(rintf(dw2[ch * 9 + t9] / s_d)) * s_d;
                    float qp = qclip(rintf(pw2[o * C_HID + ch] / s_p)) * s_p;
                    wv[p] = qd * qp;
                }
                #pragma unroll
                for (int p = 0; p < 4; ++p)
                    pk[p] = f2bf_bits(wv[2 * p]) | (f2bf_bits(wv[2 * p + 1]) << 16);
            }
            ((uint4*)W18lin)[tid] = make_uint4(pk[0], pk[1], pk[2], pk[3]);
        }

        // dotbias[o] = sum_ch qpw2[o][ch] * db2[ch]
        #pragma unroll
        for (int o = 0; o < 2; ++o) {
            __syncthreads();
            if (tid < 256) {
                float qv = qclip(rintf(pw2[o * C_HID + tid] / s_p)) * s_p;
                sm[tid] = qv * db2[tid];
            }
            __syncthreads();
            for (int s = 128; s > 0; s >>= 1) {
                if (tid < s) sm[tid] += sm[tid + s];
                __syncthreads();
            }
            if (tid == 0) scales[1 + o] = sm[0];
        }
    }
}

// ============ fused: dw1 + MFMA pw1 + ReLU + MFMA W18 -> Pg ============
// R17 tile geometry (full 128-px row, 77.8 KB LDS, 1024 blocks) but 1024
// threads = 16 waves -> 8 waves/SIMD at 2 blocks/CU. Per-wave work halves.
__global__ __launch_bounds__(1024, 8) void fused_main(
    const float* __restrict__ x,
    const float* __restrict__ qdw1T, const float* __restrict__ db1,
    const u16* __restrict__ Blin, const float* __restrict__ pb1,
    const u16* __restrict__ W18lin,
    const float* __restrict__ scales,
    float* __restrict__ Pg)
{
    __shared__ __align__(16) unsigned char smem_raw[C_HID * 132 * 2];   // 67584 B
    __shared__ float Ml[128][20];                                        // 10240 B
    u16 (*h1s)[136]  = (u16 (*)[136])smem_raw;   // phase 1-2: bf16 A-tile [px][k]
    u16 (*h2pm)[264] = (u16 (*)[264])smem_raw;   // epilogue+phase 3: h2 px-major [px][ch]

    const int bid = blockIdx.x;
    const int swz = (bid & 7) * 128 + (bid >> 3);   // XCD-bijective
    const int nb  = swz >> 6;
    const int y   = swz & 63;                        // this block's h2 row z
    const int tid = threadIdx.x;
    const int wave = tid >> 6, lane = tid & 63;

    // ---------- phase 1: depthwise 1 -> h1s (4 cin x 4 px per thread) ----------
    {
        const int q = tid & 31, g = tid >> 5;     // q: 32 px-groups, g: 32 cin-groups
        const int px0 = q << 2, cin0 = g << 2;
        // lane = (g&1)*32 + q: q-neighbors are lane-neighbors; q=0/31 masks
        // cover the half-wave boundaries, so cross-boundary shuffles are discarded.

        f32x4 bia = *(const f32x4*)(db1 + cin0);
        float a32[4][4];
        #pragma unroll
        for (int c = 0; c < 4; ++c)
            #pragma unroll
            for (int p = 0; p < 4; ++p) a32[c][p] = ((const float*)&bia)[c];

        #pragma unroll
        for (int ky = 0; ky < 3; ++ky) {
            int yy = y + ky - 1;
            if (yy < 0 || yy >= HGT) continue;
            const float* xbase = x + (((size_t)nb * C_IN + cin0) * HGT + yy) * WID;

            f32x4 mid[4];
            #pragma unroll
            for (int c = 0; c < 4; ++c)
                mid[c] = *(const f32x4*)(xbase + (size_t)c * HW + px0);

            float w3[3][4];
            #pragma unroll
            for (int kx = 0; kx < 3; ++kx) {
                f32x4 wv = *(const f32x4*)(qdw1T + (ky * 3 + kx) * C_IN + cin0);
                w3[kx][0] = wv.x; w3[kx][1] = wv.y; w3[kx][2] = wv.z; w3[kx][3] = wv.w;
            }

            #pragma unroll
            for (int c = 0; c < 4; ++c) {
                float lf = __shfl_up(mid[c].w, 1);     // lane-1's px0+3 = our px0-1
                float rt = __shfl_down(mid[c].x, 1);   // lane+1's px0   = our px0+4
                lf = (q > 0)  ? lf : 0.0f;
                rt = (q < 31) ? rt : 0.0f;
                float seg[6] = {lf, mid[c].x, mid[c].y, mid[c].z, mid[c].w, rt};
                #pragma unroll
                for (int kx = 0; kx < 3; ++kx)
                    #pragma unroll
                    for (int p = 0; p < 4; ++p)
                        a32[c][p] = fmaf(w3[kx][c], seg[p + kx], a32[c][p]);
            }
        }

        #pragma unroll
        for (int p = 0; p < 4; ++p) {
            uint2 pk;
            pk.x = f2bf_bits(a32[0][p]) | (f2bf_bits(a32[1][p]) << 16);
            pk.y = f2bf_bits(a32[2][p]) | (f2bf_bits(a32[3][p]) << 16);
            *(uint2*)&h1s[px0 + p][cin0] = pk;
        }
    }
    __syncthreads();

    // ---------- phase 2: MFMA pw1 (C = 128px x 256co over 16 waves) ----------
    const int l15 = lane & 15, l4 = lane >> 4;
    const int wpx = wave & 7;           // 8 px-tiles of 16
    const int wco = wave >> 3;          // 2 co-halves of 128
    const int px0w = wpx << 4;
    const float bscale = scales[0];

    f32x4 acc[8];
    #pragma unroll
    for (int c = 0; c < 8; ++c) acc[c] = f32x4{0, 0, 0, 0};

    const bf16x8* BL = (const bf16x8*)Blin;

    #pragma unroll
    for (int ks = 0; ks < 4; ++ks) {
        bf16x8 afrag = *(const bf16x8*)&h1s[px0w + l15][ks * 32 + l4 * 8];
        #pragma unroll
        for (int c = 0; c < 8; ++c) {
            bf16x8 bfrag = BL[(ks * 16 + wco * 8 + c) * 64 + lane];
            acc[c] = __builtin_amdgcn_mfma_f32_16x16x32_bf16(afrag, bfrag, acc[c], 0, 0, 0);
        }
    }

    __syncthreads();   // all MFMA reads of h1s complete; smem becomes h2pm

    // epilogue: scale+bias+ReLU, pack, write px-major [px][ch]
    #pragma unroll
    for (int c = 0; c < 8; ++c) {
        int co = wco * 128 + c * 16 + l15;
        int pxb = px0w + l4 * 4;
        float bias = pb1[co];
        #pragma unroll
        for (int i = 0; i < 4; ++i) {
            float v = fmaxf(fmaf(acc[c][i], bscale, bias), 0.0f);
            h2pm[pxb + i][co] = (u16)f2bf_bits(v);
        }
    }
    __syncthreads();

    // ---------- phase 3: MFMA M[128px][32j] = h2pm[128][256] x W18^T ----------
    // 16 waves = 8 px-tiles x 2 j-tiles
    {
        const int pxt3 = wave & 7;
        const int jt   = wave >> 3;
        const int px0t = pxt3 << 4;
        const bf16x8* WL = (const bf16x8*)W18lin;

        f32x4 acc2 = f32x4{0, 0, 0, 0};
        #pragma unroll 2
        for (int ks = 0; ks < 8; ++ks) {
            bf16x8 af = *(const bf16x8*)&h2pm[px0t + l15][ks * 32 + l4 * 8];
            bf16x8 bf = WL[(ks * 2 + jt) * 64 + lane];
            acc2 = __builtin_amdgcn_mfma_f32_16x16x32_bf16(af, bf, acc2, 0, 0, 0);
        }

        int j = jt * 16 + l15;
        if (j < 18) {
            #pragma unroll
            for (int i = 0; i < 4; ++i)
                Ml[px0t + l4 * 4 + i][j] = acc2[i];
        }
    }
    __syncthreads();

    // ---------- gather: P_z[ky*2+o][px] = sum_kx M[px+kx-1][(ky*3+kx)*2+o] ----------
    if (tid < 768) {
        int r = tid >> 7, px = tid & 127;
        int ky = r >> 1, o = r & 1;
        float v = 0.0f;
        #pragma unroll
        for (int kx = 0; kx < 3; ++kx) {
            int pxs = px + kx - 1;
            if (pxs >= 0 && pxs < WID)
                v += Ml[pxs][(ky * 3 + kx) * 2 + o];
        }
        Pg[((size_t)(nb * HGT + y) * 6 + r) * WID + px] = v;
    }
}

// ============ gather: out[o][y] = consts + sum_ky P_{y+ky-1}[ky*2+o] ============
__global__ __launch_bounds__(512) void gather_out(
    const float* __restrict__ Pg, const float* __restrict__ pb2,
    const float* __restrict__ scales, float* __restrict__ out)
{
    int idx = blockIdx.x * 512 + threadIdx.x;
    int px = idx & 127;
    int yy = (idx >> 7) & 63;
    int o  = (idx >> 13) & 1;
    int nb = idx >> 14;
    float v = pb2[o] + scales[1 + o];
    #pragma unroll
    for (int ky = 0; ky < 3; ++ky) {
        int z = yy + ky - 1;   // cross-correlation: tap ky reads source row y+ky-1
        if (z >= 0 && z < HGT)
            v += Pg[((size_t)(nb * HGT + z) * 6 + ky * 2 + o) * WID + px];
    }
    out[idx] = v;
}

extern "C" void kernel_launch(void* const* d_in, const int* in_sizes, int n_in,
                              void* d_out, int out_size, void* d_ws, size_t ws_size,
                              hipStream_t stream) {
    const float* x   = (const float*)d_in[0];
    const float* dw1 = (const float*)d_in[1];
    const float* db1 = (const float*)d_in[2];
    const float* pw1 = (const float*)d_in[3];
    const float* pb1 = (const float*)d_in[4];
    const float* dw2 = (const float*)d_in[5];
    const float* db2 = (const float*)d_in[6];
    const float* pw2 = (const float*)d_in[7];
    const float* pb2 = (const float*)d_in[8];
    float* out = (float*)d_out;

    char* wsb = (char*)d_ws;
    u16*   Blin   = (u16*)wsb;                          // 65536 B
    float* qdw1T  = (float*)(wsb + 65536);              // 4608 B
    float* scales = (float*)(wsb + 65536 + 4608);       // 64 B
    u16*   W18lin = (u16*)(wsb + 65536 + 4608 + 64);    // 16384 B
    float* Pg     = (float*)(wsb + 98304);              // 16*64*6*128*4 = 3 MB

    quant4_kernel<<<4, 1024, 0, stream>>>(dw1, pw1, dw2, pw2, db2,
                                          qdw1T, Blin, W18lin, scales);

    fused_main<<<NBATCH * HGT, 1024, 0, stream>>>(
        x, qdw1T, db1, Blin, pb1, W18lin, scales, Pg);

    gather_out<<<512, 512, 0, stream>>>(Pg, pb2, scales, out);
}

// Round 20
// 48.417 us; speedup vs baseline: 1.1733x; 1.1530x over previous
//
#include <hip/hip_runtime.h>
#include <math.h>

#define C_IN  128
#define C_HID 256
#define HGT   64
#define WID   128
#define NBATCH 16
#define HW (HGT * WID)

typedef unsigned int   uint32;
typedef unsigned short u16;
typedef float f32x4  __attribute__((ext_vector_type(4)));
typedef short bf16x8 __attribute__((ext_vector_type(8)));

__device__ __forceinline__ uint32 f2bf_bits(float f) {
    uint32 u = __float_as_uint(f);
    u = (u + 0x7fff + ((u >> 16) & 1)) >> 16;   // RNE
    return u;
}
__device__ __forceinline__ float qclip(float v) {
    return fminf(fmaxf(v, -128.0f), 127.0f);
}

// ============ quant: per-tensor symmetric int8 fake-quant + repack ============
// block 0: dw1 -> qdw1T[9][128]
// block 1: pw1 -> Blin (MFMA-frag bf16 ints) + scales[0]
// block 3: pw2+dw2 -> W18lin (combined dw2*pw2 weights, bf16 MFMA-frag) + dotbias
__global__ __launch_bounds__(1024) void quant4_kernel(
    const float* __restrict__ dw1, const float* __restrict__ pw1,
    const float* __restrict__ dw2, const float* __restrict__ pw2,
    const float* __restrict__ db2,
    float* __restrict__ qdw1T, u16* __restrict__ Blin,
    u16* __restrict__ W18lin, float* __restrict__ scales)
{
    const float* w; int n;
    switch (blockIdx.x) {
        case 0:  w = dw1; n = C_IN * 9;    break;
        case 1:  w = pw1; n = C_HID * C_IN; break;
        case 2:  w = dw2; n = C_HID * 9;   break;
        default: w = pw2; n = 2 * C_HID;   break;
    }
    __shared__ float sm[1024];
    int tid = threadIdx.x;
    const f32x4* w4 = (const f32x4*)w;
    int n4 = n >> 2;
    float m = 0.0f;
    #pragma unroll 4
    for (int i = tid; i < n4; i += 1024) {
        f32x4 v = w4[i];
        m = fmaxf(m, fmaxf(fmaxf(fabsf(v.x), fabsf(v.y)),
                           fmaxf(fabsf(v.z), fabsf(v.w))));
    }
    sm[tid] = m;
    __syncthreads();
    for (int s = 512; s > 0; s >>= 1) {
        if (tid < s) sm[tid] = fmaxf(sm[tid], sm[tid + s]);
        __syncthreads();
    }
    const float scale = sm[0] / 127.0f;

    if (blockIdx.x == 0) {
        for (int i = tid; i < C_IN * 9; i += 1024) {
            int t = i >> 7, cin = i & 127;
            float v = qclip(rintf(dw1[cin * 9 + t] / scale));
            qdw1T[i] = v * scale;
        }
    } else if (blockIdx.x == 1) {
        if (tid == 0) scales[0] = scale;
        // slot s = (kstep*16 + cofrag)*64 + lane; each slot = 8 bf16 (16B)
        #pragma unroll
        for (int i = tid; i < 4096; i += 1024) {
            int kstep = i >> 10;
            int cf    = (i >> 6) & 15;
            int l     = i & 63;
            int co    = cf * 16 + (l & 15);
            int k0    = kstep * 32 + ((l >> 4) << 3);
            const float* src = pw1 + (size_t)co * C_IN + k0;
            f32x4 a = *(const f32x4*)src;
            f32x4 b = *(const f32x4*)(src + 4);
            float vv[8] = {a.x, a.y, a.z, a.w, b.x, b.y, b.z, b.w};
            uint32 pk[4];
            #pragma unroll
            for (int p = 0; p < 4; ++p) {
                float v0 = qclip(rintf(vv[2 * p]     / scale));
                float v1 = qclip(rintf(vv[2 * p + 1] / scale));
                pk[p] = f2bf_bits(v0) | (f2bf_bits(v1) << 16);   // ints exact in bf16
            }
            ((uint4*)Blin)[i] = make_uint4(pk[0], pk[1], pk[2], pk[3]);
        }
    } else if (blockIdx.x == 2) {
        // dw2 handled in block 3
    } else {
        const float s_p = scale;   // pw2 scale
        __syncthreads();

        // second reduction: max|dw2| (2304 = 576 f32x4)
        const f32x4* d4 = (const f32x4*)dw2;
        float md = 0.0f;
        for (int i = tid; i < 576; i += 1024) {
            f32x4 v = d4[i];
            md = fmaxf(md, fmaxf(fmaxf(fabsf(v.x), fabsf(v.y)),
                                 fmaxf(fabsf(v.z), fabsf(v.w))));
        }
        sm[tid] = md;
        __syncthreads();
        for (int s = 512; s > 0; s >>= 1) {
            if (tid < s) sm[tid] = fmaxf(sm[tid], sm[tid + s]);
            __syncthreads();
        }
        const float s_d = sm[0] / 127.0f;

        // W18lin: slot = (ks*2 + jt)*64 + lane; j = jt*16 + (lane&15),
        // ch0 = ks*32 + (lane>>4)*8. W18[j][ch] = qdw2(ch, j>>1) * qpw2(j&1, ch).
        {
            int ks  = tid >> 7;
            int jt  = (tid >> 6) & 1;
            int l   = tid & 63;
            int j   = jt * 16 + (l & 15);
            int ch0 = ks * 32 + ((l >> 4) << 3);
            uint32 pk[4] = {0, 0, 0, 0};
            if (j < 18) {
                int t9 = j >> 1, o = j & 1;
                float wv[8];
                #pragma unroll
                for (int p = 0; p < 8; ++p) {
                    int ch = ch0 + p;
                    float qd = qclip(rintf(dw2[ch * 9 + t9] / s_d)) * s_d;
                    float qp = qclip(rintf(pw2[o * C_HID + ch] / s_p)) * s_p;
                    wv[p] = qd * qp;
                }
                #pragma unroll
                for (int p = 0; p < 4; ++p)
                    pk[p] = f2bf_bits(wv[2 * p]) | (f2bf_bits(wv[2 * p + 1]) << 16);
            }
            ((uint4*)W18lin)[tid] = make_uint4(pk[0], pk[1], pk[2], pk[3]);
        }

        // dotbias[o] = sum_ch qpw2[o][ch] * db2[ch]
        #pragma unroll
        for (int o = 0; o < 2; ++o) {
            __syncthreads();
            if (tid < 256) {
                float qv = qclip(rintf(pw2[o * C_HID + tid] / s_p)) * s_p;
                sm[tid] = qv * db2[tid];
            }
            __syncthreads();
            for (int s = 128; s > 0; s >>= 1) {
                if (tid < s) sm[tid] += sm[tid + s];
                __syncthreads();
            }
            if (tid == 0) scales[1 + o] = sm[0];
        }
    }
}

// ============ fused: dw1 + MFMA pw1 + ReLU + MFMA dw2/pw2 -> Pg ============
// R17 champion configuration: 512 threads, 77.8 KB LDS, 2 blocks/CU, VGPR 64.
__global__ __launch_bounds__(512, 4) void fused_main(
    const float* __restrict__ x,
    const float* __restrict__ qdw1T, const float* __restrict__ db1,
    const u16* __restrict__ Blin, const float* __restrict__ pb1,
    const u16* __restrict__ W18lin,
    const float* __restrict__ scales,
    float* __restrict__ Pg)
{
    __shared__ __align__(16) unsigned char smem_raw[C_HID * 132 * 2];   // 67584 B
    __shared__ float Ml[128][20];                                        // 10240 B
    u16 (*h1s)[136]  = (u16 (*)[136])smem_raw;   // phase 1-2: bf16 A-tile (px-major, k contig)
    u16 (*h2pm)[264] = (u16 (*)[264])smem_raw;   // epilogue+phase 3: h2 px-major [px][ch]

    const int bid = blockIdx.x;
    const int swz = (bid & 7) * 128 + (bid >> 3);   // XCD-bijective
    const int nb  = swz >> 6;
    const int y   = swz & 63;                        // this block's h2 row z
    const int tid = threadIdx.x;
    const int wave = tid >> 6, lane = tid & 63;

    // ---------- phase 1: depthwise 1 -> h1s (8 coalesced loads/ky; halo via shfl) ----------
    {
        const int q = tid & 31, g = tid >> 5;
        const int px0 = q << 2, cin0 = g << 3;
        // lane = (g&1)*32 + q: q boundaries coincide with half-wave boundaries,
        // so cross-boundary shuffle values are always masked to zero.

        f32x4 bia = *(const f32x4*)(db1 + cin0);
        f32x4 bib = *(const f32x4*)(db1 + cin0 + 4);
        float a32[8][4];
        #pragma unroll
        for (int c = 0; c < 8; ++c) {
            float b = (c < 4) ? ((const float*)&bia)[c] : ((const float*)&bib)[c - 4];
            #pragma unroll
            for (int p = 0; p < 4; ++p) a32[c][p] = b;
        }

        #pragma unroll
        for (int ky = 0; ky < 3; ++ky) {
            int yy = y + ky - 1;
            if (yy < 0 || yy >= HGT) continue;
            const float* xbase = x + (((size_t)nb * C_IN + cin0) * HGT + yy) * WID;

            f32x4 mid[8];
            #pragma unroll
            for (int c = 0; c < 8; ++c)
                mid[c] = *(const f32x4*)(xbase + (size_t)c * HW + px0);

            float w3[3][8];
            #pragma unroll
            for (int kx = 0; kx < 3; ++kx) {
                f32x4 wa = *(const f32x4*)(qdw1T + (ky * 3 + kx) * C_IN + cin0);
                f32x4 wb = *(const f32x4*)(qdw1T + (ky * 3 + kx) * C_IN + cin0 + 4);
                w3[kx][0] = wa.x; w3[kx][1] = wa.y; w3[kx][2] = wa.z; w3[kx][3] = wa.w;
                w3[kx][4] = wb.x; w3[kx][5] = wb.y; w3[kx][6] = wb.z; w3[kx][7] = wb.w;
            }

            #pragma unroll
            for (int c = 0; c < 8; ++c) {
                float lf = __shfl_up(mid[c].w, 1);     // lane-1's px0-1
                float rt = __shfl_down(mid[c].x, 1);   // lane+1's px0+4
                lf = (q > 0)  ? lf : 0.0f;
                rt = (q < 31) ? rt : 0.0f;
                float seg[6] = {lf, mid[c].x, mid[c].y, mid[c].z, mid[c].w, rt};
                #pragma unroll
                for (int kx = 0; kx < 3; ++kx)
                    #pragma unroll
                    for (int p = 0; p < 4; ++p)
                        a32[c][p] = fmaf(w3[kx][c], seg[p + kx], a32[c][p]);
            }
        }

        #pragma unroll
        for (int p = 0; p < 4; ++p) {
            uint32 pk[4];
            #pragma unroll
            for (int i = 0; i < 4; ++i)
                pk[i] = f2bf_bits(a32[2 * i][p]) | (f2bf_bits(a32[2 * i + 1][p]) << 16);
            *(uint4*)&h1s[px0 + p][cin0] = make_uint4(pk[0], pk[1], pk[2], pk[3]);
        }
    }
    __syncthreads();

    // ---------- phase 2: MFMA pw1 ----------
    const int l15 = lane & 15, l4 = lane >> 4;
    const int wco = wave >> 2;          // 0..1: co half
    const int wpx = wave & 3;           // 0..3: 32-px quarter
    const int px0w = wpx << 5;
    const float bscale = scales[0];

    f32x4 acc[2][8];
    #pragma unroll
    for (int f = 0; f < 2; ++f)
        #pragma unroll
        for (int c = 0; c < 8; ++c) acc[f][c] = f32x4{0, 0, 0, 0};

    const bf16x8* BL = (const bf16x8*)Blin;

    #pragma unroll
    for (int ks = 0; ks < 4; ++ks) {
        bf16x8 bfrag[8];
        #pragma unroll
        for (int c = 0; c < 8; ++c)
            bfrag[c] = BL[(ks * 16 + wco * 8 + c) * 64 + lane];
        bf16x8 afrag[2];
        #pragma unroll
        for (int f = 0; f < 2; ++f)
            afrag[f] = *(const bf16x8*)&h1s[px0w + f * 16 + l15][ks * 32 + l4 * 8];
        #pragma unroll
        for (int f = 0; f < 2; ++f)
            #pragma unroll
            for (int c = 0; c < 8; ++c)
                acc[f][c] = __builtin_amdgcn_mfma_f32_16x16x32_bf16(
                    afrag[f], bfrag[c], acc[f][c], 0, 0, 0);
    }

    __syncthreads();   // all MFMA reads of h1s complete; smem becomes h2pm

    // epilogue: scale+bias+ReLU, pack, write px-major [px][ch] (b16 writes)
    #pragma unroll
    for (int f = 0; f < 2; ++f) {
        int pxb = px0w + f * 16 + l4 * 4;
        #pragma unroll
        for (int c = 0; c < 8; ++c) {
            int co = wco * 128 + c * 16 + l15;
            float bias = pb1[co];
            float v0 = fmaxf(fmaf(acc[f][c].x, bscale, bias), 0.0f);
            float v1 = fmaxf(fmaf(acc[f][c].y, bscale, bias), 0.0f);
            float v2 = fmaxf(fmaf(acc[f][c].z, bscale, bias), 0.0f);
            float v3 = fmaxf(fmaf(acc[f][c].w, bscale, bias), 0.0f);
            h2pm[pxb + 0][co] = (u16)f2bf_bits(v0);
            h2pm[pxb + 1][co] = (u16)f2bf_bits(v1);
            h2pm[pxb + 2][co] = (u16)f2bf_bits(v2);
            h2pm[pxb + 3][co] = (u16)f2bf_bits(v3);
        }
    }
    __syncthreads();

    // ---------- phase 3: MFMA M[128px][32j] = h2pm[128][256] x W18^T ----------
    // wave w owns px-tile [w*16, w*16+16)
    {
        const int px0t = wave << 4;
        const bf16x8* WL = (const bf16x8*)W18lin;

        f32x4 acc2[2];
        acc2[0] = f32x4{0, 0, 0, 0};
        acc2[1] = f32x4{0, 0, 0, 0};

        #pragma unroll 2
        for (int ks = 0; ks < 8; ++ks) {
            bf16x8 af = *(const bf16x8*)&h2pm[px0t + l15][ks * 32 + l4 * 8];
            bf16x8 b0 = WL[(ks * 2 + 0) * 64 + lane];
            bf16x8 b1 = WL[(ks * 2 + 1) * 64 + lane];
            acc2[0] = __builtin_amdgcn_mfma_f32_16x16x32_bf16(af, b0, acc2[0], 0, 0, 0);
            acc2[1] = __builtin_amdgcn_mfma_f32_16x16x32_bf16(af, b1, acc2[1], 0, 0, 0);
        }

        // D layout: col = lane&15 (j), row = l4*4 + i (px within tile)
        #pragma unroll
        for (int i = 0; i < 4; ++i)
            Ml[px0t + l4 * 4 + i][l15] = acc2[0][i];
        if (l15 < 2) {
            #pragma unroll
            for (int i = 0; i < 4; ++i)
                Ml[px0t + l4 * 4 + i][16 + l15] = acc2[1][i];
        }
    }
    __syncthreads();

    // ---------- gather: P_z[ky*2+o][px] = sum_kx M[px+kx-1][(ky*3+kx)*2+o] ----------
    for (int t = tid; t < 768; t += 512) {
        int r = t >> 7, px = t & 127;
        int ky = r >> 1, o = r & 1;
        float v = 0.0f;
        #pragma unroll
        for (int kx = 0; kx < 3; ++kx) {
            int pxs = px + kx - 1;
            if (pxs >= 0 && pxs < WID)
                v += Ml[pxs][(ky * 3 + kx) * 2 + o];
        }
        Pg[((size_t)(nb * HGT + y) * 6 + r) * WID + px] = v;
    }
}

// ============ gather: out[o][y] = consts + sum_ky P_{y+ky-1}[ky*2+o] ============
__global__ __launch_bounds__(512) void gather_out(
    const float* __restrict__ Pg, const float* __restrict__ pb2,
    const float* __restrict__ scales, float* __restrict__ out)
{
    int idx = blockIdx.x * 512 + threadIdx.x;
    int px = idx & 127;
    int yy = (idx >> 7) & 63;
    int o  = (idx >> 13) & 1;
    int nb = idx >> 14;
    float v = pb2[o] + scales[1 + o];
    #pragma unroll
    for (int ky = 0; ky < 3; ++ky) {
        int z = yy + ky - 1;   // cross-correlation: tap ky reads source row y+ky-1
        if (z >= 0 && z < HGT)
            v += Pg[((size_t)(nb * HGT + z) * 6 + ky * 2 + o) * WID + px];
    }
    out[idx] = v;
}

extern "C" void kernel_launch(void* const* d_in, const int* in_sizes, int n_in,
                              void* d_out, int out_size, void* d_ws, size_t ws_size,
                              hipStream_t stream) {
    const float* x   = (const float*)d_in[0];
    const float* dw1 = (const float*)d_in[1];
    const float* db1 = (const float*)d_in[2];
    const float* pw1 = (const float*)d_in[3];
    const float* pb1 = (const float*)d_in[4];
    const float* dw2 = (const float*)d_in[5];
    const float* db2 = (const float*)d_in[6];
    const float* pw2 = (const float*)d_in[7];
    const float* pb2 = (const float*)d_in[8];
    float* out = (float*)d_out;

    char* wsb = (char*)d_ws;
    u16*   Blin   = (u16*)wsb;                          // 65536 B
    float* qdw1T  = (float*)(wsb + 65536);              // 4608 B
    float* scales = (float*)(wsb + 65536 + 4608);       // 64 B
    u16*   W18lin = (u16*)(wsb + 65536 + 4608 + 64);    // 16384 B
    float* Pg     = (float*)(wsb + 98304);              // 16*64*6*128*4 = 3 MB

    quant4_kernel<<<4, 1024, 0, stream>>>(dw1, pw1, dw2, pw2, db2,
                                          qdw1T, Blin, W18lin, scales);

    fused_main<<<NBATCH * HGT, 512, 0, stream>>>(
        x, qdw1T, db1, Blin, pb1, W18lin, scales, Pg);

    gather_out<<<512, 512, 0, stream>>>(Pg, pb2, scales, out);
}